// Round 4
// baseline (188.102 us; speedup 1.0000x reference)
//
#include <hip/hip_runtime.h>
#include <math.h>

#define T_LEN 256
#define HID 10

typedef float v2f __attribute__((ext_vector_type(2)));

__device__ __forceinline__ v2f mk2(float a, float b) { v2f r; r.x = a; r.y = b; return r; }
__device__ __forceinline__ v2f splat2(float a) { return mk2(a, a); }

// setup-only accurate softplus
__device__ __forceinline__ float softplus_f(float x) {
    return fmaxf(x, 0.0f) + log1pf(expf(-fabsf(x)));
}
__device__ __forceinline__ float samp(const float* mu, const float* rho,
                                      const float* eps, int i) {
    return mu[i] + softplus_f(rho[i]) * eps[i];
}

// sigmoid = rcp(1 + 2^(-log2e*x))
__device__ __forceinline__ float fast_sigmoid(float x) {
    float e = __builtin_amdgcn_exp2f(-1.442695040888963f * x);
    return __builtin_amdgcn_rcpf(1.0f + e);
}
// tanh(x) = 1 - 2/(2^(2*log2e*x)+1)
__device__ __forceinline__ float fast_tanh(float x) {
    float e = __builtin_amdgcn_exp2f(2.885390081777927f * x);
    return fmaf(-2.0f, __builtin_amdgcn_rcpf(e + 1.0f), 1.0f);
}

// DPP row rotate-right by R within each 16-lane row (VALU pipe, no DS):
// dst lane i = src lane (i - R) mod 16.
#define ROTF(hi, R) __int_as_float(__builtin_amdgcn_mov_dpp((hi), 0x120 + (R), 0xF, 0xF, true))

struct Wreg {
    // wsel01[r] = whh row ((k - r) & 15), col pair {i,f} of this lane's unit k
    // (zero for pad rows >= HID and pad lanes k >= HID)
    v2f wsel01[16], wsel23[16];
    v2f wih01, wih23, b01, b23;
};

// One LSTM step. h is distributed: lane k of each 16-lane row holds h[k]
// (lanes 10..15 hold 0). The 10x40 matvec is done with 15 independent DPP
// rotations of hk, each feeding 2 pk-FMAs against the pre-permuted weights.
__device__ __forceinline__ float lstm_step(const Wreg& w, float xt, float hk,
                                           float& c)
{
    const int hi = __float_as_int(hk);
    v2f x2 = splat2(xt);
    v2f e01 = __builtin_elementwise_fma(x2, w.wih01, w.b01);
    v2f e23 = __builtin_elementwise_fma(x2, w.wih23, w.b23);
    v2f o01 = w.wsel01[0] * splat2(hk);
    v2f o23 = w.wsel23[0] * splat2(hk);
#define RSTEP(R, A01, A23)                                            \
    {                                                                 \
        v2f hr = splat2(ROTF(hi, R));                                 \
        A01 = __builtin_elementwise_fma(hr, w.wsel01[R], A01);        \
        A23 = __builtin_elementwise_fma(hr, w.wsel23[R], A23);        \
    }
    RSTEP(1,  e01, e23)
    RSTEP(2,  o01, o23)
    RSTEP(3,  e01, e23)
    RSTEP(4,  o01, o23)
    RSTEP(5,  e01, e23)
    RSTEP(6,  o01, o23)
    RSTEP(7,  e01, e23)
    RSTEP(8,  o01, o23)
    RSTEP(9,  e01, e23)
    RSTEP(10, o01, o23)
    RSTEP(11, e01, e23)
    RSTEP(12, o01, o23)
    RSTEP(13, e01, e23)
    RSTEP(14, o01, o23)
    RSTEP(15, e01, e23)
#undef RSTEP
    v2f a01 = e01 + o01;
    v2f a23 = e23 + o23;
    float ig = fast_sigmoid(a01.x);
    float fg = fast_sigmoid(a01.y);
    float gg = fast_tanh(a23.x);
    float og = fast_sigmoid(a23.y);
    c = fmaf(fg, c, ig * gg);
    return og * fast_tanh(c);
}

// One wave per block; 4 elements per wave, one per 16-lane row. 8192/4 = 2048
// waves = exactly 2 per SIMD. NO DS ops in the recurrence: h-exchange is DPP
// (VALU pipe), x is loaded redundantly per lane (same address across the row,
// L1-broadcast) with one float4 chunk prefetched ahead.
__global__ __launch_bounds__(64) void bayes_lstm_kernel(
    const float* __restrict__ x,
    const float* __restrict__ w_ih_mu, const float* __restrict__ w_ih_rho,
    const float* __restrict__ w_hh_mu, const float* __restrict__ w_hh_rho,
    const float* __restrict__ b_mu,    const float* __restrict__ b_rho,
    const float* __restrict__ eps_ih,  const float* __restrict__ eps_hh,
    const float* __restrict__ eps_b,
    const float* __restrict__ lin_w,   const float* __restrict__ lin_b,
    float* __restrict__ out, int n_elem)
{
    const int lane = threadIdx.x & 63;
    const int k    = lane & 15;          // unit index within row (pads: 10..15)
    const int g    = lane >> 4;          // 0..3: element slot within wave
    const int b    = blockIdx.x * 4 + g;
    const int b_eff = (b < n_elem) ? b : (n_elem - 1);   // clamp for safe loads
    const bool un  = (k < HID);

    // ---- sample weights into registers, pre-permuted for the rotation ----
    Wreg w;
    w.wih01 = splat2(0.f); w.wih23 = splat2(0.f);
    w.b01 = splat2(0.f);   w.b23 = splat2(0.f);
    if (un) {
        const int c0 = k, c1 = HID + k, c2 = 2 * HID + k, c3 = 3 * HID + k;
        w.wih01 = mk2(samp(w_ih_mu, w_ih_rho, eps_ih, c0), samp(w_ih_mu, w_ih_rho, eps_ih, c1));
        w.wih23 = mk2(samp(w_ih_mu, w_ih_rho, eps_ih, c2), samp(w_ih_mu, w_ih_rho, eps_ih, c3));
        w.b01   = mk2(samp(b_mu, b_rho, eps_b, c0), samp(b_mu, b_rho, eps_b, c1));
        w.b23   = mk2(samp(b_mu, b_rho, eps_b, c2), samp(b_mu, b_rho, eps_b, c3));
    }
#pragma unroll
    for (int r = 0; r < 16; ++r) {
        const int idx = (k - r) & 15;    // source h index delivered by ROTF(r)
        if (un && idx < HID) {
            const int base = idx * 4 * HID;
            w.wsel01[r] = mk2(samp(w_hh_mu, w_hh_rho, eps_hh, base + k),
                              samp(w_hh_mu, w_hh_rho, eps_hh, base + HID + k));
            w.wsel23[r] = mk2(samp(w_hh_mu, w_hh_rho, eps_hh, base + 2 * HID + k),
                              samp(w_hh_mu, w_hh_rho, eps_hh, base + 3 * HID + k));
        } else {
            w.wsel01[r] = splat2(0.f);
            w.wsel23[r] = splat2(0.f);
        }
    }

    // ---- recurrence: 64 chunks x 4 steps, x prefetched one chunk ahead ----
    float c = 0.f, hk = 0.f;   // pad lanes: zero weights keep hk == 0 forever
    const float4* xv = (const float4*)(x + (size_t)b_eff * T_LEN);
    float4 xq = xv[0];
    for (int ch = 0; ch < 64; ++ch) {
        const int nx = (ch < 63) ? ch + 1 : 63;
        float4 xn = xv[nx];
        hk = lstm_step(w, xq.x, hk, c);
        hk = lstm_step(w, xq.y, hk, c);
        hk = lstm_step(w, xq.z, hk, c);
        hk = lstm_step(w, xq.w, hk, c);
        xq = xn;
    }

    // ---- linear head: reduce h[k]*lw over the 16-lane row ----
    const float lw = un ? lin_w[k] : 0.f;
    float pa = hk * lw;                  // pad lanes contribute 0
    pa += __shfl_xor(pa, 1, 16);
    pa += __shfl_xor(pa, 2, 16);
    pa += __shfl_xor(pa, 4, 16);
    pa += __shfl_xor(pa, 8, 16);
    if (k == 0 && b < n_elem) out[b] = pa + lin_b[0];
}

extern "C" void kernel_launch(void* const* d_in, const int* in_sizes, int n_in,
                              void* d_out, int out_size, void* d_ws, size_t ws_size,
                              hipStream_t stream) {
    const float* x        = (const float*)d_in[0];
    const float* w_ih_mu  = (const float*)d_in[1];
    const float* w_ih_rho = (const float*)d_in[2];
    const float* w_hh_mu  = (const float*)d_in[3];
    const float* w_hh_rho = (const float*)d_in[4];
    const float* b_mu     = (const float*)d_in[5];
    const float* b_rho    = (const float*)d_in[6];
    const float* eps_ih   = (const float*)d_in[7];
    const float* eps_hh   = (const float*)d_in[8];
    const float* eps_b    = (const float*)d_in[9];
    const float* lin_w    = (const float*)d_in[10];
    const float* lin_b    = (const float*)d_in[11];
    float* out = (float*)d_out;

    const int n_b = in_sizes[0] / T_LEN;     // 8192
    dim3 grid((n_b + 3) / 4), block(64);     // 1 wave/block, 4 elements/wave
    hipLaunchKernelGGL(bayes_lstm_kernel, grid, block, 0, stream,
                       x, w_ih_mu, w_ih_rho, w_hh_mu, w_hh_rho, b_mu, b_rho,
                       eps_ih, eps_hh, eps_b, lin_w, lin_b, out, n_b);
}

// Round 5
// 168.334 us; speedup vs baseline: 1.1174x; 1.1174x over previous
//
#include <hip/hip_runtime.h>
#include <math.h>

#define T_LEN 256
#define HID 10

typedef float v2f __attribute__((ext_vector_type(2)));

__device__ __forceinline__ v2f mk2(float a, float b) { v2f r; r.x = a; r.y = b; return r; }
__device__ __forceinline__ v2f splat2(float a) { return mk2(a, a); }

// setup-only accurate softplus
__device__ __forceinline__ float softplus_f(float x) {
    return fmaxf(x, 0.0f) + log1pf(expf(-fabsf(x)));
}
__device__ __forceinline__ float samp(const float* mu, const float* rho,
                                      const float* eps, int i) {
    return mu[i] + softplus_f(rho[i]) * eps[i];
}

#define NLOG2E (-1.442695040888963f)   // i,f,o columns pre-scale
#define P2LOG2E (2.885390081777927f)   // g column pre-scale

// activations on PRE-SCALED gate inputs (scale folded into weights):
// sigmoid(x) = rcp(1 + exp2(-log2e*x))     -> input already -log2e*x
__device__ __forceinline__ float sig_pre(float a) {
    return __builtin_amdgcn_rcpf(1.0f + __builtin_amdgcn_exp2f(a));
}
// tanh(x) = 1 - 2*rcp(exp2(2log2e*x)+1)    -> input already 2log2e*x
__device__ __forceinline__ float tanh_pre(float a) {
    return fmaf(-2.0f, __builtin_amdgcn_rcpf(__builtin_amdgcn_exp2f(a) + 1.0f), 1.0f);
}
// runtime tanh for c (not pre-scalable)
__device__ __forceinline__ float fast_tanh(float x) {
    float e = __builtin_amdgcn_exp2f(P2LOG2E * x);
    return fmaf(-2.0f, __builtin_amdgcn_rcpf(e + 1.0f), 1.0f);
}

struct Wreg {
    v2f whh01[HID], whh23[HID];   // recurrent cols {i,f} / {g,o}, PRE-SCALED
    v2f wih01, wih23, b01, b23;   // pre-scaled
};

// one LSTM step; h in 3 float4s (h[0..9] + 2 pad). 4-deep FMA tree.
__device__ __forceinline__ float lstm_step(const Wreg& w, float xt,
                                           float4 h0, float4 h1, float4 h2,
                                           float& c)
{
    v2f x2 = splat2(xt);
    // four independent chains per gate-pair, combined with 2 add levels
    v2f A1 = __builtin_elementwise_fma(x2, w.wih01, w.b01);
    v2f A3 = __builtin_elementwise_fma(x2, w.wih23, w.b23);
    A1 = __builtin_elementwise_fma(splat2(h0.x), w.whh01[0], A1);
    A3 = __builtin_elementwise_fma(splat2(h0.x), w.whh23[0], A3);
    v2f B1 = w.whh01[2] * splat2(h0.z);
    v2f B3 = w.whh23[2] * splat2(h0.z);
    v2f C1 = w.whh01[1] * splat2(h0.y);
    v2f C3 = w.whh23[1] * splat2(h0.y);
    v2f D1 = w.whh01[3] * splat2(h0.w);
    v2f D3 = w.whh23[3] * splat2(h0.w);
    A1 = __builtin_elementwise_fma(splat2(h1.x), w.whh01[4], A1);
    A3 = __builtin_elementwise_fma(splat2(h1.x), w.whh23[4], A3);
    B1 = __builtin_elementwise_fma(splat2(h1.z), w.whh01[6], B1);
    B3 = __builtin_elementwise_fma(splat2(h1.z), w.whh23[6], B3);
    C1 = __builtin_elementwise_fma(splat2(h1.y), w.whh01[5], C1);
    C3 = __builtin_elementwise_fma(splat2(h1.y), w.whh23[5], C3);
    D1 = __builtin_elementwise_fma(splat2(h1.w), w.whh01[7], D1);
    D3 = __builtin_elementwise_fma(splat2(h1.w), w.whh23[7], D3);
    A1 = __builtin_elementwise_fma(splat2(h2.x), w.whh01[8], A1);
    A3 = __builtin_elementwise_fma(splat2(h2.x), w.whh23[8], A3);
    C1 = __builtin_elementwise_fma(splat2(h2.y), w.whh01[9], C1);
    C3 = __builtin_elementwise_fma(splat2(h2.y), w.whh23[9], C3);
    v2f a01 = (A1 + B1) + (C1 + D1);
    v2f a23 = (A3 + B3) + (C3 + D3);
    float ig = sig_pre(a01.x);
    float fg = sig_pre(a01.y);
    float gg = tanh_pre(a23.x);
    float og = sig_pre(a23.y);
    c = fmaf(fg, c, ig * gg);
    return og * fast_tanh(c);
}

// One wave per block; 6 elements per wave, one per 10-lane group (lanes 60..63
// ride along on a dummy 7th group slot). h in LDS at stride 20 floats
// (bank-disjoint b128 reads). x loaded per-lane as float4 (group-uniform addr,
// L1-broadcast) -> NO shuffles/bpermutes in the DS queue. h-reads for step t+1
// are issued immediately after step t's write so the back-edge + seed work
// overlaps the LDS round trip.
__global__ __launch_bounds__(64) void bayes_lstm_kernel(
    const float* __restrict__ x,
    const float* __restrict__ w_ih_mu, const float* __restrict__ w_ih_rho,
    const float* __restrict__ w_hh_mu, const float* __restrict__ w_hh_rho,
    const float* __restrict__ b_mu,    const float* __restrict__ b_rho,
    const float* __restrict__ eps_ih,  const float* __restrict__ eps_hh,
    const float* __restrict__ eps_b,
    const float* __restrict__ lin_w,   const float* __restrict__ lin_b,
    float* __restrict__ out, int n_elem)
{
    __shared__ __align__(16) float hbuf[7 * 20];  // 6 real groups + 1 dummy

    const int lane = threadIdx.x;        // 0..63
    const int g    = lane / 10;          // 0..6 (6 = dummy, lanes 60..63)
    const int k    = lane - g * 10;      // 0..9
    const int b    = blockIdx.x * 6 + g;
    const bool valid = (g < 6) && (b < n_elem);
    const int b_eff = valid ? b : 0;     // clamp for safe loads
    float* hb = hbuf + g * 20;

    // ---- sample weights into registers, PRE-SCALED by activation consts ----
    Wreg w;
    const int c0 = k, c1 = HID + k, c2 = 2 * HID + k, c3 = 3 * HID + k;
    const v2f s01 = mk2(NLOG2E, NLOG2E);      // {i, f}
    const v2f s23 = mk2(P2LOG2E, NLOG2E);     // {g, o}
    w.wih01 = s01 * mk2(samp(w_ih_mu, w_ih_rho, eps_ih, c0), samp(w_ih_mu, w_ih_rho, eps_ih, c1));
    w.wih23 = s23 * mk2(samp(w_ih_mu, w_ih_rho, eps_ih, c2), samp(w_ih_mu, w_ih_rho, eps_ih, c3));
    w.b01   = s01 * mk2(samp(b_mu, b_rho, eps_b, c0), samp(b_mu, b_rho, eps_b, c1));
    w.b23   = s23 * mk2(samp(b_mu, b_rho, eps_b, c2), samp(b_mu, b_rho, eps_b, c3));
#pragma unroll
    for (int j = 0; j < HID; ++j) {
        w.whh01[j] = s01 * mk2(samp(w_hh_mu, w_hh_rho, eps_hh, j * 4 * HID + c0),
                               samp(w_hh_mu, w_hh_rho, eps_hh, j * 4 * HID + c1));
        w.whh23[j] = s23 * mk2(samp(w_hh_mu, w_hh_rho, eps_hh, j * 4 * HID + c2),
                               samp(w_hh_mu, w_hh_rho, eps_hh, j * 4 * HID + c3));
    }
    const float lw = lin_w[k];

    // zero the 2 pad floats so b128 reads of h[8..11] see zeros
    if (k < 2) hb[10 + k] = 0.f;

    float c = 0.f, hk = 0.f;
    float4 h0 = make_float4(0.f, 0.f, 0.f, 0.f);   // h starts at 0: no LDS
    float4 h1 = h0, h2 = h0;                       // round trip before step 0
    const float4* xv = (const float4*)(x + (size_t)b_eff * T_LEN);
    const float4* p  = (const float4*)hb;
    float4 xq = xv[0];

    for (int ch = 0; ch < 64; ++ch) {    // 64 chunks x 4 steps = 256
        const int nx = (ch < 63) ? ch + 1 : 63;
        float4 xn = xv[nx];              // prefetch next chunk
#pragma unroll
        for (int ti = 0; ti < 4; ++ti) {
            float xt = (ti == 0) ? xq.x : (ti == 1) ? xq.y : (ti == 2) ? xq.z : xq.w;
            hk = lstm_step(w, xt, h0, h1, h2, c);
            hb[k] = hk;                  // write own h (same-wave DS in-order)
            h0 = p[0]; h1 = p[1]; h2 = p[2];   // read back for NEXT step now:
        }                                // back-edge + seeds overlap DS latency
        xq = xn;
    }

    // ---- linear head: reduce h[k]*lw over the 10-lane group via LDS ----
    hb[k] = hk * lw;                     // pads at 10,11 still zero
    if (k == 0 && valid) {
        float4 s0 = p[0], s1 = p[1], s2 = p[2];
        out[b] = (s0.x + s0.y + s0.z + s0.w)
               + (s1.x + s1.y + s1.z + s1.w)
               + (s2.x + s2.y + s2.z + s2.w) + lin_b[0];
    }
}

extern "C" void kernel_launch(void* const* d_in, const int* in_sizes, int n_in,
                              void* d_out, int out_size, void* d_ws, size_t ws_size,
                              hipStream_t stream) {
    const float* x        = (const float*)d_in[0];
    const float* w_ih_mu  = (const float*)d_in[1];
    const float* w_ih_rho = (const float*)d_in[2];
    const float* w_hh_mu  = (const float*)d_in[3];
    const float* w_hh_rho = (const float*)d_in[4];
    const float* b_mu     = (const float*)d_in[5];
    const float* b_rho    = (const float*)d_in[6];
    const float* eps_ih   = (const float*)d_in[7];
    const float* eps_hh   = (const float*)d_in[8];
    const float* eps_b    = (const float*)d_in[9];
    const float* lin_w    = (const float*)d_in[10];
    const float* lin_b    = (const float*)d_in[11];
    float* out = (float*)d_out;

    const int n_b = in_sizes[0] / T_LEN;     // 8192
    dim3 grid((n_b + 5) / 6), block(64);     // 1 wave/block, 6 elements/wave
    hipLaunchKernelGGL(bayes_lstm_kernel, grid, block, 0, stream,
                       x, w_ih_mu, w_ih_rho, w_hh_mu, w_hh_rho, b_mu, b_rho,
                       eps_ih, eps_hh, eps_b, lin_w, lin_b, out, n_b);
}